// Round 9
// baseline (198.799 us; speedup 1.0000x reference)
//
#include <hip/hip_runtime.h>
#include <math.h>

#define DISP  3
#define IMGH  56
#define IMGW  56

typedef __attribute__((ext_vector_type(8))) __bf16 bf16x8;
typedef __attribute__((ext_vector_type(4))) __bf16 bf16x4;
typedef __attribute__((ext_vector_type(4))) short short4v;
typedef __attribute__((ext_vector_type(4))) float f32x4;

__device__ __forceinline__ short f2bf(float f) {
  unsigned u = __builtin_bit_cast(unsigned, f);
  unsigned r = (u + 0x7fffu + ((u >> 16) & 1u)) >> 16;
  return (short)r;
}
__device__ __forceinline__ float bf2f(short s) {
  unsigned u = ((unsigned)(unsigned short)s) << 16;
  return __builtin_bit_cast(float, u);
}

// ---------------- prep kernel (unchanged): fused weights + bias tables into d_ws ----
// ws layout (shorts): [0..1280) Wqkt[32][40]  (Wqkt[n][k] = scale*(Wq^T Wk)[k][n])
//                     [1280..2560) W2r[32][40] (W2r[m][n] = (Wl@Wv)[m][n])
//                     [2560..2560+13328) bias[4][49][68] bf16 (variant = mrow*2+mcol)
__global__ void prep_kernel(const float* __restrict__ Wq, const float* __restrict__ Wk,
                            const float* __restrict__ Wv, const float* __restrict__ Wl,
                            const float* __restrict__ pe, short* __restrict__ wsW,
                            short* __restrict__ wsB) {
  __shared__ float lw[4096];
  __shared__ float lpe[176];
  const int t = threadIdx.x;
  const int gid = blockIdx.x * 256 + t;   // 16 blocks x 256
  for (int i = t; i < 1024; i += 256) {
    lw[i] = Wq[i]; lw[1024 + i] = Wk[i]; lw[2048 + i] = Wv[i]; lw[3072 + i] = Wl[i];
  }
  if (t < 169) lpe[t] = pe[t];
  __syncthreads();
  if (gid < 1024) {
    int k = gid >> 5, n = gid & 31; float acc = 0.f;
    #pragma unroll
    for (int d = 0; d < 32; d++) acc += lw[d * 32 + k] * lw[1024 + d * 32 + n];
    wsW[n * 40 + k] = f2bf(acc * 0.17677669529663687f);
  } else if (gid < 2048) {
    int e = gid - 1024; int m = e >> 5, n = e & 31; float acc = 0.f;
    #pragma unroll
    for (int d = 0; d < 32; d++) acc += lw[3072 + m * 32 + d] * lw[2048 + d * 32 + n];
    wsW[1280 + m * 40 + n] = f2bf(acc);
  }
  for (int e = gid; e < 13328; e += 4096) {
    int v = e / 3332, r2 = e % 3332, q = r2 / 68, k = r2 % 68;
    float val;
    if (k >= 49) val = -INFINITY;
    else {
      int qy = q / 7, qx = q % 7, ky = k / 7, kx = k % 7;
      bool masked = ((v & 2) && ((qy >= 4) != (ky >= 4))) ||
                    ((v & 1) && ((qx >= 4) != (kx >= 4)));
      val = masked ? -INFINITY : lpe[(ky - qy + 6) * 13 + (kx - qx + 6)];
    }
    wsB[e] = f2bf(val);
  }
}

// ---------------- main kernel: block=(b,win), 4 waves, 2 heads/wave ----------------
// LDS (bytes): 0 wqkt[32][40]bf | 2560 w2r[32][40]bf | 5120 gaddr[64]i | 5376 arenas 4x11024
// arena: Tb[64][36]bf (4608) overlaid by Pb[49][68]bf (6664/pad 6672); UT[32][68]bf at 6672
// bias lives in 16 short4v registers per lane (loaded direct from global, both heads share)
__global__ __launch_bounds__(256, 3) void swca_kernel(
    const float* __restrict__ skip, const float* __restrict__ x,
    const short* __restrict__ wsW, const short* __restrict__ wsB,
    float* __restrict__ out) {
  __shared__ __align__(16) char smem[49472];
  __bf16* wqkt  = (__bf16*)smem;
  __bf16* w2r   = (__bf16*)(smem + 2560);
  int*    gaddr = (int*)(smem + 5120);
  char*   arena = smem + 5376;

  const int t = threadIdx.x, blk = blockIdx.x;
  const int win = blk & 63, b = blk >> 6, wy = win >> 3, wx = win & 7;
  const int w = t >> 6, l = t & 63;
  const int lrow = l & 15, g = l >> 4, lk8 = g * 8;

  // ---- bias fragments -> registers (issued first; independent of LDS/barrier) ----
  short4v bias[4][4];
  {
    int v = ((wy == 7) ? 2 : 0) | ((wx == 7) ? 1 : 0);
    const short* bb = wsB + v * 3332;
    #pragma unroll
    for (int tj = 0; tj < 4; tj++) {
      int q = tj * 16 + lrow; int qc = q > 48 ? 48 : q;
      #pragma unroll
      for (int ti = 0; ti < 4; ti++)
        bias[tj][ti] = *(const short4v*)(bb + qc * 68 + ti * 16 + g * 4);
    }
  }

  // ---- weights -> LDS; gather addresses ----
  {
    const int* wsrc = (const int*)wsW;
    int* wdst = (int*)smem;
    for (int i = t; i < 1280; i += 256) wdst[i] = wsrc[i];
    if (t < 64) {
      int p = t, ga = 0;
      if (p < 49) {
        int py = p / 7, px = p % 7;
        int r = (wy * 7 + py + DISP) % IMGH, c = (wx * 7 + px + DISP) % IMGW;
        ga = (b * 3136 + r * 56 + c) * 256;
      }
      gaddr[t] = ga;
    }
  }
  __syncthreads();

  __bf16* Tb = (__bf16*)(arena + w * 11024);
  __bf16* Pb = Tb;
  __bf16* UT = (__bf16*)(arena + w * 11024 + 6672);

  // ---- prefetch + convert BOTH heads' A fragments (one exposed HBM latency) ----
  bf16x8 axh[2][4], ash[2][4];
  #pragma unroll
  for (int hh = 0; hh < 2; hh++) {
    const int h = w * 2 + hh;
    #pragma unroll
    for (int tm = 0; tm < 4; tm++) {
      bf16x8 a, s;
      #pragma unroll
      for (int j = 0; j < 8; j++) { a[j] = (__bf16)0.0f; s[j] = (__bf16)0.0f; }
      int p = tm * 16 + lrow;
      if (p < 49) {
        int ga = gaddr[p] + h * 32 + lk8;
        float4 x0 = *(const float4*)(x + ga);
        float4 x1 = *(const float4*)(x + ga + 4);
        float4 s0 = *(const float4*)(skip + ga);
        float4 s1 = *(const float4*)(skip + ga + 4);
        a[0]=(__bf16)x0.x; a[1]=(__bf16)x0.y; a[2]=(__bf16)x0.z; a[3]=(__bf16)x0.w;
        a[4]=(__bf16)x1.x; a[5]=(__bf16)x1.y; a[6]=(__bf16)x1.z; a[7]=(__bf16)x1.w;
        s[0]=(__bf16)s0.x; s[1]=(__bf16)s0.y; s[2]=(__bf16)s0.z; s[3]=(__bf16)s0.w;
        s[4]=(__bf16)s1.x; s[5]=(__bf16)s1.y; s[6]=(__bf16)s1.z; s[7]=(__bf16)s1.w;
      }
      axh[hh][tm] = a; ash[hh][tm] = s;
    }
  }

  const f32x4 zero = {0.f, 0.f, 0.f, 0.f};

  #pragma unroll
  for (int hh = 0; hh < 2; hh++) {
    const int h = w * 2 + hh;
    bf16x8 bq[2], bw[2];
    #pragma unroll
    for (int tn = 0; tn < 2; tn++) {
      int n = tn * 16 + lrow;
      bq[tn] = *(const bf16x8*)(wqkt + n * 40 + lk8);
      bw[tn] = *(const bf16x8*)(w2r  + n * 40 + lk8);
    }
    // ---- T = X@Wqk -> Tb ; U = S@W2^T -> UT ----
    #pragma unroll
    for (int tm = 0; tm < 4; tm++) {
      int row0 = tm * 16 + g * 4;
      #pragma unroll
      for (int tn = 0; tn < 2; tn++) {
        int col = tn * 16 + lrow;
        f32x4 tD = __builtin_amdgcn_mfma_f32_16x16x32_bf16(axh[hh][tm], bq[tn], zero, 0, 0, 0);
        Tb[(row0 + 0) * 36 + col] = (__bf16)tD[0];
        Tb[(row0 + 1) * 36 + col] = (__bf16)tD[1];
        Tb[(row0 + 2) * 36 + col] = (__bf16)tD[2];
        Tb[(row0 + 3) * 36 + col] = (__bf16)tD[3];
        f32x4 uD = __builtin_amdgcn_mfma_f32_16x16x32_bf16(ash[hh][tm], bw[tn], zero, 0, 0, 0);
        bf16x4 u4 = {(__bf16)uD[0], (__bf16)uD[1], (__bf16)uD[2], (__bf16)uD[3]};
        *(bf16x4*)(UT + col * 68 + row0) = u4;
      }
    }
    // ---- S^T = X @ T^T, per-tj: 4 MFMA -> softmax -> P store (low st liveness) ----
    bf16x8 bT[4];
    #pragma unroll
    for (int tn = 0; tn < 4; tn++) {
      int n = tn * 16 + lrow;
      bf16x4 lo = *(const bf16x4*)(Tb + n * 36 + lk8);
      bf16x4 hi = *(const bf16x4*)(Tb + n * 36 + lk8 + 4);
      bT[tn] = __builtin_shufflevector(lo, hi, 0, 1, 2, 3, 4, 5, 6, 7);
    }
    #pragma unroll
    for (int tj = 0; tj < 4; tj++) {
      f32x4 stj[4];
      #pragma unroll
      for (int ti = 0; ti < 4; ti++)
        stj[ti] = __builtin_amdgcn_mfma_f32_16x16x32_bf16(axh[hh][ti], bT[tj], zero, 0, 0, 0);
      int q = tj * 16 + lrow;
      float vv[4][4]; float mx = -INFINITY;
      #pragma unroll
      for (int ti = 0; ti < 4; ti++) {
        vv[ti][0] = stj[ti][0] + bf2f(bias[tj][ti][0]);
        vv[ti][1] = stj[ti][1] + bf2f(bias[tj][ti][1]);
        vv[ti][2] = stj[ti][2] + bf2f(bias[tj][ti][2]);
        vv[ti][3] = stj[ti][3] + bf2f(bias[tj][ti][3]);
        mx = fmaxf(mx, fmaxf(fmaxf(vv[ti][0], vv[ti][1]), fmaxf(vv[ti][2], vv[ti][3])));
      }
      mx = fmaxf(mx, __shfl_xor(mx, 16));
      mx = fmaxf(mx, __shfl_xor(mx, 32));
      float sum = 0.f;
      #pragma unroll
      for (int ti = 0; ti < 4; ti++) {
        vv[ti][0] = __expf(vv[ti][0] - mx); sum += vv[ti][0];
        vv[ti][1] = __expf(vv[ti][1] - mx); sum += vv[ti][1];
        vv[ti][2] = __expf(vv[ti][2] - mx); sum += vv[ti][2];
        vv[ti][3] = __expf(vv[ti][3] - mx); sum += vv[ti][3];
      }
      sum += __shfl_xor(sum, 16);
      sum += __shfl_xor(sum, 32);
      float inv = 1.f / sum;
      if (q < 49) {
        #pragma unroll
        for (int ti = 0; ti < 4; ti++) {
          bf16x4 p4 = {(__bf16)(vv[ti][0] * inv), (__bf16)(vv[ti][1] * inv),
                       (__bf16)(vv[ti][2] * inv), (__bf16)(vv[ti][3] * inv)};
          *(bf16x4*)(Pb + q * 68 + ti * 16 + g * 4) = p4;
        }
      }
    }
    // ---- out = P @ U (rows q>=49 of Pb are garbage but only feed discarded D rows) ----
    f32x4 oD[4][2];
    #pragma unroll
    for (int tr = 0; tr < 4; tr++)
      #pragma unroll
      for (int tn = 0; tn < 2; tn++) oD[tr][tn] = zero;
    #pragma unroll
    for (int ks = 0; ks < 2; ks++) {
      int kof = ks * 32 + lk8;
      bf16x8 aP[4], bU[2];
      #pragma unroll
      for (int tr = 0; tr < 4; tr++) {
        int q = tr * 16 + lrow;
        bf16x4 lo = *(const bf16x4*)(Pb + q * 68 + kof);
        bf16x4 hi = *(const bf16x4*)(Pb + q * 68 + kof + 4);
        aP[tr] = __builtin_shufflevector(lo, hi, 0, 1, 2, 3, 4, 5, 6, 7);
      }
      #pragma unroll
      for (int tn = 0; tn < 2; tn++) {
        int n = tn * 16 + lrow;
        bf16x4 lo = *(const bf16x4*)(UT + n * 68 + kof);
        bf16x4 hi = *(const bf16x4*)(UT + n * 68 + kof + 4);
        bU[tn] = __builtin_shufflevector(lo, hi, 0, 1, 2, 3, 4, 5, 6, 7);
      }
      #pragma unroll
      for (int tr = 0; tr < 4; tr++)
        #pragma unroll
        for (int tn = 0; tn < 2; tn++)
          oD[tr][tn] = __builtin_amdgcn_mfma_f32_16x16x32_bf16(aP[tr], bU[tn], oD[tr][tn], 0, 0, 0);
    }
    // ---- store ----
    #pragma unroll
    for (int tr = 0; tr < 4; tr++) {
      int p0 = tr * 16 + g * 4;
      #pragma unroll
      for (int r = 0; r < 4; r++) {
        int p = p0 + r;
        if (p < 49) {
          int ga = gaddr[p] + h * 32;
          out[ga + lrow]      = oD[tr][0][r];
          out[ga + 16 + lrow] = oD[tr][1][r];
        }
      }
    }
  }
}

extern "C" void kernel_launch(void* const* d_in, const int* in_sizes, int n_in,
                              void* d_out, int out_size, void* d_ws, size_t ws_size,
                              hipStream_t stream) {
  const float* skip = (const float*)d_in[0];
  const float* x    = (const float*)d_in[1];
  const float* Wq   = (const float*)d_in[2];
  const float* Wk   = (const float*)d_in[3];
  const float* Wv   = (const float*)d_in[4];
  const float* Wl   = (const float*)d_in[5];
  const float* pe   = (const float*)d_in[6];
  float* out = (float*)d_out;
  short* wsW = (short*)d_ws;
  short* wsB = wsW + 2560;

  prep_kernel<<<16, 256, 0, stream>>>(Wq, Wk, Wv, Wl, pe, wsW, wsB);
  swca_kernel<<<16 * 64, 256, 0, stream>>>(skip, x, wsW, wsB, out);
}